// Round 7
// baseline (133.985 us; speedup 1.0000x reference)
//
#include <hip/hip_runtime.h>
#include <math.h>

#define B 4
#define C 384
#define HIN 224
#define WIN 224
#define KS 14
#define HB 16
#define WBL 16
#define P 196
#define HW (HIN * WIN)   // 50176
#define CG 2             // channel groups in gemv pass
#define CPG (C / CG)     // 192
#define NT 49            // hw tiles of 1024 floats per batch

// ---------------------------------------------------------------------------
// Kernel 1: GEMV-style partial rowsum (unchanged from round 3 — streams at
// ~6.7 TB/s). Block = (b, hw-tile of 1024 floats, channel-group of 192).
// ---------------------------------------------------------------------------
__global__ __launch_bounds__(256) void k_gemv(const float* __restrict__ hr,
                                              const float* __restrict__ attn_w,
                                              float* __restrict__ part) {
    __shared__ float wlds[CPG];
    const int tid = threadIdx.x;
    const int cg = blockIdx.x & 1;
    const int t  = (blockIdx.x >> 1) % NT;
    const int b  = blockIdx.x / (2 * NT);
    if (tid < CPG) wlds[tid] = attn_w[cg * CPG + tid];
    __syncthreads();

    const float* base = hr + (size_t)(b * C + cg * CPG) * HW + t * 1024 + tid * 4;
    float4 acc = make_float4(0.f, 0.f, 0.f, 0.f);
    #pragma unroll 8
    for (int c = 0; c < CPG; ++c) {
        const float4 v = *reinterpret_cast<const float4*>(base + (size_t)c * HW);
        const float wc = wlds[c];
        acc.x += v.x * wc; acc.y += v.y * wc; acc.z += v.z * wc; acc.w += v.w * wc;
    }
    reinterpret_cast<float4*>(part + (size_t)(b * CG + cg) * HW + t * 1024)[tid] = acc;
}

// ---------------------------------------------------------------------------
// Kernel 2 (fused): softmax + weighted patch reduction.
// One block per (b, hb, 8-channel group); grid 3072, cg fastest.
// Phase A (2 block syncs total): gather strip logits from part, per-wb
//   softmax (wave w owns wb = 4w..4w+3), unnormalized e kept in LDS
//   at [ki][w] layout co-laid with hr rows.
// Phase B (NO block syncs): each wave independently processes 2 channels;
//   lane owns columns {l, l+64, l+128, l+192<32}, scalar coalesced loads
//   (256B/instr), per-wave colsum in LDS, 16 lanes do the 14->1 kj-reduce
//   and store out/S.
// ---------------------------------------------------------------------------
__global__ __launch_bounds__(256) void k_fused3(const float* __restrict__ hr,
                                                const float* __restrict__ part,
                                                const float* __restrict__ attn_b,
                                                const float* __restrict__ w_kk,
                                                const float* __restrict__ b_kk,
                                                const int* __restrict__ mask,
                                                float* __restrict__ out) {
    __shared__ float e_lds[KS * WIN];       // 12544 floats, [ki][w]
    __shared__ float wkk[P], bkk[P];
    __shared__ float Swb[WBL], maskv[WBL];
    __shared__ float colsum[4][WIN];        // per-wave private
    const int tid = threadIdx.x;
    const int wave = tid >> 6, lane = tid & 63;
    const int cg = blockIdx.x % 48;
    const int hb = (blockIdx.x / 48) & 15;
    const int b  = blockIdx.x / (48 * 16);

    if (tid < P) { wkk[tid] = w_kk[tid]; bkk[tid] = b_kk[tid]; }
    if (tid >= 224 && tid < 240) maskv[tid - 224] = mask[(b * HB + hb) * WBL + (tid - 224)] ? 1.f : 0.f;
    __syncthreads();

    // ---- phase A1: strip logits into e_lds ----
    const float ab = attn_b[0];
    const float* p0 = part + (size_t)(b * CG + 0) * HW + (size_t)(hb * KS) * WIN;
    const float* p1 = part + (size_t)(b * CG + 1) * HW + (size_t)(hb * KS) * WIN;
    for (int i = tid; i < KS * WIN; i += 256) {
        const int ki = i / WIN, w = i % WIN;
        const int wb = w / KS, kj = w - wb * KS;
        const int p = ki * KS + kj;
        const float rv = p0[i] + p1[i];
        e_lds[i] = (rv + ab) * maskv[wb] * wkk[p] + bkk[p];
    }
    __syncthreads();

    // ---- phase A2: per-wb softmax (wave w owns wb = 4w + 0..3) ----
    #pragma unroll
    for (int wbi = 0; wbi < 4; ++wbi) {
        const int wb = wave * 4 + wbi;
        float m = -INFINITY;
        for (int p = lane; p < P; p += 64)
            m = fmaxf(m, e_lds[(p / KS) * WIN + wb * KS + (p % KS)]);
        #pragma unroll
        for (int off = 32; off; off >>= 1) m = fmaxf(m, __shfl_xor(m, off));
        float s = 0.f;
        for (int p = lane; p < P; p += 64) {
            const int idx = (p / KS) * WIN + wb * KS + (p % KS);
            const float e = __expf(e_lds[idx] - m);
            e_lds[idx] = e;
            s += e;
        }
        #pragma unroll
        for (int off = 32; off; off >>= 1) s += __shfl_xor(s, off);
        if (lane == 0) Swb[wb] = s;
    }
    __syncthreads();

    // ---- phase B: per-wave independent channel loop (no block syncs) ----
    #pragma unroll
    for (int cc = 0; cc < 2; ++cc) {
        const int c = cg * 8 + wave * 2 + cc;
        const float* hbase = hr + ((size_t)(b * C + c) * HIN + hb * KS) * WIN;
        float a0 = 0.f, a1 = 0.f, a2 = 0.f, a3 = 0.f;
        #pragma unroll
        for (int ki = 0; ki < KS; ++ki) {
            const float* hrow = hbase + (size_t)ki * WIN;
            const float* erow = e_lds + ki * WIN;
            a0 += hrow[lane]       * erow[lane];
            a1 += hrow[lane + 64]  * erow[lane + 64];
            a2 += hrow[lane + 128] * erow[lane + 128];
            if (lane < 32) a3 += hrow[lane + 192] * erow[lane + 192];
        }
        colsum[wave][lane] = a0;
        colsum[wave][lane + 64] = a1;
        colsum[wave][lane + 128] = a2;
        if (lane < 32) colsum[wave][lane + 192] = a3;
        if (lane < WBL) {
            float s = 0.f;
            #pragma unroll
            for (int k = 0; k < KS; ++k) s += colsum[wave][lane * KS + k];
            out[((size_t)(b * C + c) * HB + hb) * WBL + lane] = s / Swb[lane];
        }
    }
}

extern "C" void kernel_launch(void* const* d_in, const int* in_sizes, int n_in,
                              void* d_out, int out_size, void* d_ws, size_t ws_size,
                              hipStream_t stream) {
    const float* hr      = (const float*)d_in[0];  // (4,384,224,224)
    // d_in[1] = guidance (unused)
    const float* attn_w  = (const float*)d_in[2];  // (1,384)
    const float* attn_b  = (const float*)d_in[3];  // (1,)
    const float* w_kk    = (const float*)d_in[4];  // (14,14)
    const float* b_kk    = (const float*)d_in[5];  // (14,14)
    const int*   mask    = (const int*)d_in[6];    // (4,16,16,1) bool->int
    float* out = (float*)d_out;                    // (4,384,16,16)

    float* part = (float*)d_ws;                    // B*CG*HW floats (1.6MB)

    k_gemv<<<B * NT * CG, 256, 0, stream>>>(hr, attn_w, part);
    k_fused3<<<B * 16 * 48, 256, 0, stream>>>(hr, part, attn_b, w_kk, b_kk, mask, out);
}

// Round 8
// 104.559 us; speedup vs baseline: 1.2814x; 1.2814x over previous
//
#include <hip/hip_runtime.h>
#include <math.h>

#define B 4
#define C 384
#define HIN 224
#define WIN 224
#define KS 14
#define HB 16
#define WBL 16
#define P 196
#define HW (HIN * WIN)   // 50176
#define CG 2             // channel groups in gemv pass
#define CPG (C / CG)     // 192
#define NT 49            // hw tiles of 1024 floats per batch
#define NC 16            // channels per k3 block (4 per wave)

// ---------------------------------------------------------------------------
// Kernel 1: GEMV-style partial rowsum (round-3 version — streams ~6.7 TB/s).
// Block = (b, hw-tile of 1024 floats, channel-group of 192).
// ---------------------------------------------------------------------------
__global__ __launch_bounds__(256) void k_gemv(const float* __restrict__ hr,
                                              const float* __restrict__ attn_w,
                                              float* __restrict__ part) {
    __shared__ float wlds[CPG];
    const int tid = threadIdx.x;
    const int cg = blockIdx.x & 1;
    const int t  = (blockIdx.x >> 1) % NT;
    const int b  = blockIdx.x / (2 * NT);
    if (tid < CPG) wlds[tid] = attn_w[cg * CPG + tid];
    __syncthreads();

    const float* base = hr + (size_t)(b * C + cg * CPG) * HW + t * 1024 + tid * 4;
    float4 acc = make_float4(0.f, 0.f, 0.f, 0.f);
    #pragma unroll 8
    for (int c = 0; c < CPG; ++c) {
        const float4 v = *reinterpret_cast<const float4*>(base + (size_t)c * HW);
        const float wc = wlds[c];
        acc.x += v.x * wc; acc.y += v.y * wc; acc.z += v.z * wc; acc.w += v.w * wc;
    }
    reinterpret_cast<float4*>(part + (size_t)(b * CG + cg) * HW + t * 1024)[tid] = acc;
}

// ---------------------------------------------------------------------------
// Kernel 2: logits -> softmax -> attn[b,hb,wb,p] (normalized). Unchanged.
// ---------------------------------------------------------------------------
__global__ __launch_bounds__(256) void k_softmax(const float* __restrict__ part,
                                                 const float* __restrict__ attn_b,
                                                 const float* __restrict__ w_kk,
                                                 const float* __restrict__ b_kk,
                                                 const int* __restrict__ mask,
                                                 float* __restrict__ attn) {
    const int blk = blockIdx.x;        // 0 .. B*HB*WBL-1
    const int wb = blk % WBL;
    const int hb = (blk / WBL) % HB;
    const int b = blk / (WBL * HB);
    const int tid = threadIdx.x;

    float logit = 0.f;
    float l = -INFINITY;
    if (tid < P) {
        const int ki = tid / KS, kj = tid % KS;
        const size_t idx = (size_t)(hb * KS + ki) * WIN + wb * KS + kj;
        const float rv = part[(size_t)(b * CG + 0) * HW + idx]
                       + part[(size_t)(b * CG + 1) * HW + idx];
        const float m = mask[(b * HB + hb) * WBL + wb] ? 1.f : 0.f;
        logit = (rv + attn_b[0]) * m * w_kk[tid] + b_kk[tid];
        l = logit;
    }

    __shared__ float smax[4], ssum[4];
    float v = l;
    #pragma unroll
    for (int off = 32; off; off >>= 1) v = fmaxf(v, __shfl_xor(v, off));
    if ((tid & 63) == 0) smax[tid >> 6] = v;
    __syncthreads();
    const float bm = fmaxf(fmaxf(smax[0], smax[1]), fmaxf(smax[2], smax[3]));

    float e = (tid < P) ? __expf(logit - bm) : 0.f;
    float s = e;
    #pragma unroll
    for (int off = 32; off; off >>= 1) s += __shfl_xor(s, off);
    if ((tid & 63) == 0) ssum[tid >> 6] = s;
    __syncthreads();
    const float bs = ssum[0] + ssum[1] + ssum[2] + ssum[3];

    if (tid < P) attn[(size_t)blk * P + tid] = e / bs;
}

// ---------------------------------------------------------------------------
// Kernel 3: out[b,c,hb,wb] = sum_p hr_patch[p,c] * attn[b,hb,wb,p]
// One block per (b,hb,16-channel group). Attn staged ONCE in [ki][w] layout
// (one sync), then a fully wave-independent channel loop: wave owns 4
// channels, 56 lanes do float4 row-dots (896B/instr over a contiguous
// 12.5KB strip), per-wave private colsum slab (intra-wave LDS needs no
// barrier), 16 lanes finish the kj-reduce and store. ZERO syncs after stage.
// ---------------------------------------------------------------------------
__global__ __launch_bounds__(256) void k_weighted(const float* __restrict__ hr,
                                                  const float* __restrict__ attn,
                                                  float* __restrict__ out) {
    __shared__ float e_lds[KS * WIN];       // 12.25 KB, [ki][w] co-laid with hr rows
    __shared__ float colsum[4][WIN];        // per-wave private slabs
    const int tid = threadIdx.x;
    const int wave = tid >> 6, lane = tid & 63;
    const int cg = blockIdx.x % (C / NC);        // 24, fastest: attn L2 reuse
    const int hb = (blockIdx.x / (C / NC)) & 15;
    const int b  = blockIdx.x / ((C / NC) * 16);

    const float* abase = attn + (size_t)((b * HB + hb) * WBL) * P;
    for (int i = tid; i < WBL * P; i += 256) {
        const int wb = i / P, p = i % P;
        e_lds[(p / KS) * WIN + wb * KS + (p % KS)] = abase[i];
    }
    __syncthreads();

    #pragma unroll
    for (int cc = 0; cc < NC / 4; ++cc) {
        const int c = cg * NC + wave * (NC / 4) + cc;
        const float* hbase = hr + (size_t)((b * C + c) * HIN + hb * KS) * WIN;
        if (lane < 56) {
            float4 acc = make_float4(0.f, 0.f, 0.f, 0.f);
            #pragma unroll
            for (int ki = 0; ki < KS; ++ki) {
                const float4 v = *reinterpret_cast<const float4*>(hbase + ki * WIN + lane * 4);
                const float4 e = *reinterpret_cast<const float4*>(e_lds + ki * WIN + lane * 4);
                acc.x += v.x * e.x; acc.y += v.y * e.y;
                acc.z += v.z * e.z; acc.w += v.w * e.w;
            }
            *reinterpret_cast<float4*>(&colsum[wave][lane * 4]) = acc;
        }
        // intra-wave LDS dependency: lockstep wave + compiler waitcnt, no barrier
        if (lane < WBL) {
            float s = 0.f;
            #pragma unroll
            for (int k = 0; k < KS; ++k) s += colsum[wave][lane * KS + k];
            out[(size_t)((b * C + c) * HB + hb) * WBL + lane] = s;
        }
    }
}

extern "C" void kernel_launch(void* const* d_in, const int* in_sizes, int n_in,
                              void* d_out, int out_size, void* d_ws, size_t ws_size,
                              hipStream_t stream) {
    const float* hr      = (const float*)d_in[0];  // (4,384,224,224)
    // d_in[1] = guidance (unused)
    const float* attn_w  = (const float*)d_in[2];  // (1,384)
    const float* attn_b  = (const float*)d_in[3];  // (1,)
    const float* w_kk    = (const float*)d_in[4];  // (14,14)
    const float* b_kk    = (const float*)d_in[5];  // (14,14)
    const int*   mask    = (const int*)d_in[6];    // (4,16,16,1) bool->int
    float* out = (float*)d_out;                    // (4,384,16,16)

    float* part = (float*)d_ws;                           // B*CG*HW floats (1.6MB)
    float* attn = part + (size_t)B * CG * HW;             // B*HB*WBL*P floats (802KB)

    k_gemv<<<B * NT * CG, 256, 0, stream>>>(hr, attn_w, part);
    k_softmax<<<B * HB * WBL, 256, 0, stream>>>(part, attn_b, w_kk, b_kk, mask, attn);
    k_weighted<<<B * 16 * (C / NC), 256, 0, stream>>>(hr, attn, out);
}